// Round 2
// baseline (339.624 us; speedup 1.0000x reference)
//
#include <hip/hip_runtime.h>
#include <math.h>

#define LOD 64
#define LSD 128
#define KK 16
#define BB 128
#define TT 96
#define OBSD 128
#define ENC 512
#define CH 128
#define OUTD 64
#define TMS 17   // tm_s row stride (odd -> 2-way bank alias max, free)

__device__ __forceinline__ float elup1f(float x) {
    return x >= 0.0f ? x + 1.0f : expf(x);
}

// ---------------- prep: band-compress basis ----------------
// basis[k][row][s], row in [0,128), s in [0,14). s<7: left block col = r-3+s; s>=7: right block.
__global__ void prep_basis(const float* __restrict__ tm11, const float* __restrict__ tm12,
                           const float* __restrict__ tm21, const float* __restrict__ tm22,
                           float* __restrict__ basis) {
    int e = blockIdx.x * blockDim.x + threadIdx.x;
    if (e >= 16 * 128 * 14) return;
    int k = e / (128 * 14);
    int rem = e % (128 * 14);
    int row = rem / 14;
    int s = rem % 14;
    int r = row & 63;
    int half = row >> 6;
    int sub = (s >= 7) ? 1 : 0;
    int ss = s - sub * 7;
    int col = r - 3 + ss;
    float v = 0.0f;
    if (col >= 0 && col < 64) {
        const float* src = half ? (sub ? tm22 : tm21) : (sub ? tm12 : tm11);
        v = src[k * 4096 + r * 64 + col];
    }
    basis[e] = v;
}

// ---------------- encoder (unchanged from R1) ----------------
#define EROWS 16
__global__ __launch_bounds__(256, 2)
void encoder_kernel(const float* __restrict__ obs,
                    const float* __restrict__ enc_W, const float* __restrict__ enc_b,
                    const float* __restrict__ wmean_W, const float* __restrict__ wmean_b,
                    const float* __restrict__ wcov_W, const float* __restrict__ wcov_b,
                    float* __restrict__ wm_out, float* __restrict__ wc_out) {
    __shared__ float obs_s[EROWS][OBSD];
    __shared__ float h_s[EROWS][ENC];
    __shared__ float wm_s[EROWS][LOD];
    __shared__ float norm_s[EROWS];
    int tid = threadIdx.x;
    long row0 = (long)blockIdx.x * EROWS;

    for (int idx = tid; idx < EROWS * OBSD; idx += 256) {
        int r = idx >> 7, c = idx & 127;
        obs_s[r][c] = obs[(row0 + r) * OBSD + c];
    }
    __syncthreads();

    for (int p = 0; p < 2; ++p) {
        int c = tid + p * 256;
        float acc[EROWS];
        #pragma unroll
        for (int r = 0; r < EROWS; ++r) acc[r] = 0.f;
        for (int j = 0; j < OBSD; ++j) {
            float w = enc_W[j * ENC + c];
            #pragma unroll
            for (int r = 0; r < EROWS; ++r) acc[r] += obs_s[r][j] * w;
        }
        float b = enc_b[c];
        #pragma unroll
        for (int r = 0; r < EROWS; ++r) h_s[r][c] = fmaxf(acc[r] + b, 0.f);
    }
    __syncthreads();

    {
        int c = tid & 63, g = tid >> 6;
        const float* W = (g < 2) ? wmean_W : wcov_W;
        int r0 = (g & 1) * 8;
        float acc[8];
        #pragma unroll
        for (int r = 0; r < 8; ++r) acc[r] = 0.f;
        for (int j = 0; j < ENC; ++j) {
            float w = W[j * LOD + c];
            #pragma unroll
            for (int r = 0; r < 8; ++r) acc[r] += h_s[r0 + r][j] * w;
        }
        if (g < 2) {
            float b = wmean_b[c];
            #pragma unroll
            for (int r = 0; r < 8; ++r) wm_s[r0 + r][c] = acc[r] + b;
        } else {
            float b = wcov_b[c];
            #pragma unroll
            for (int r = 0; r < 8; ++r)
                wc_out[(row0 + r0 + r) * LOD + c] = elup1f(acc[r] + b);
        }
    }
    __syncthreads();
    if (tid < EROWS) {
        float ss = 0.f;
        for (int c = 0; c < 64; ++c) { float v = wm_s[tid][c]; ss += v * v; }
        norm_s[tid] = sqrtf(ss);
    }
    __syncthreads();
    for (int idx = tid; idx < EROWS * LOD; idx += 256) {
        int r = idx >> 6, c = idx & 63;
        wm_out[(row0 + r) * LOD + c] = wm_s[r][c] / norm_s[r];
    }
}

// ---------------- scan: 3 barriers/step ----------------
// Phase A  (tid<128): hh[c] = relu(mean . cW1[:,c] + b1[c]), full column in regs.
// Phase CDE (all):    per-wave redundant logits+softmax via shuffles (no LDS),
//                     then banded Tm from register basis -> tm_s (stride 17).
// Phase FG (tid<64):  per-row ncu/ncl/ncs/new_mean + Kalman update + carry write.
__global__ __launch_bounds__(256, 1)
void scan_kernel(const float* __restrict__ wm_g, const float* __restrict__ wc_g,
                 const float* __restrict__ cW1, const float* __restrict__ cb1,
                 const float* __restrict__ cW2, const float* __restrict__ cb2,
                 const float* __restrict__ basis, const float* __restrict__ log_tc,
                 float* __restrict__ post_g) {
    __shared__ __align__(16) float mean_s[LSD];
    __shared__ __align__(16) float hh_s[LSD];
    __shared__ float tm_s[128 * TMS];
    __shared__ float meanU[70], meanL[70], cuP[70], clP[70], csP[70]; // +/-3 zero pad

    int tid = threadIdx.x;
    int b = blockIdx.x;
    int l = tid & 63;
    int k = l & 15;       // logit index this lane owns
    int p = l >> 4;       // j-chunk (32 wide) this lane covers

    // --- persistent register state ---
    float br[16][7];      // banded basis, entries e = m*256+tid for all k
    #pragma unroll
    for (int q = 0; q < 16; ++q)
        #pragma unroll
        for (int m = 0; m < 7; ++m)
            br[q][m] = basis[q * 1792 + m * 256 + tid];

    int ta[7];
    #pragma unroll
    for (int m = 0; m < 7; ++m) {
        int e = m * 256 + tid;
        ta[m] = (e / 14) * TMS + (e % 14);
    }

    float w1r[128];       // full cW1 column for c = tid (threads < 128)
    if (tid < 128) {
        #pragma unroll
        for (int j = 0; j < 128; ++j)
            w1r[j] = cW1[j * 128 + tid];
    }
    float cb1r = cb1[tid & 127];

    float w2r[32];        // cW2[(32p+u)][k] for this lane's (k,p)
    #pragma unroll
    for (int u = 0; u < 32; ++u)
        w2r[u] = cW2[(p * 32 + u) * 16 + k];
    float cb2r = cb2[k];

    float tcu_r = 0.f, tcl_r = 0.f;
    if (tid < 64) {
        tcu_r = elup1f(log_tc[tid]);
        tcl_r = elup1f(log_tc[64 + tid]);
    }

    // --- init carry ---
    if (tid < 70) {
        meanU[tid] = 0.f; meanL[tid] = 0.f; csP[tid] = 0.f;
        float c0 = (tid >= 3 && tid < 67) ? 10.0f : 0.f;
        cuP[tid] = c0; clP[tid] = c0;
    }
    if (tid < 128) mean_s[tid] = 0.f;
    __syncthreads();

    for (int t = 0; t < TT; ++t) {
        long rg = (long)b * TT + t;
        float wmv = 0.f, wcv = 0.f;
        if (tid < 64) {                    // prefetch; consumed in FG
            wmv = wm_g[rg * 64 + tid];
            wcv = wc_g[rg * 64 + tid];
        }

        // ---- A: hh (full-column dot, no reduce) ----
        if (tid < 128) {
            float a0 = 0.f, a1 = 0.f, a2 = 0.f, a3 = 0.f;
            const float4* m4p = (const float4*)mean_s;
            #pragma unroll
            for (int j = 0; j < 32; ++j) {
                float4 m4 = m4p[j];
                a0 += w1r[4 * j + 0] * m4.x;
                a1 += w1r[4 * j + 1] * m4.y;
                a2 += w1r[4 * j + 2] * m4.z;
                a3 += w1r[4 * j + 3] * m4.w;
            }
            hh_s[tid] = fmaxf(a0 + a1 + a2 + a3 + cb1r, 0.f);
        }
        __syncthreads();

        // ---- CDE: per-wave redundant coeff, then banded Tm ----
        {
            float acc = 0.f;
            const float4* hp = (const float4*)(hh_s + p * 32);
            #pragma unroll
            for (int u = 0; u < 8; ++u) {
                float4 h4 = hp[u];
                acc += h4.x * w2r[4 * u + 0] + h4.y * w2r[4 * u + 1]
                     + h4.z * w2r[4 * u + 2] + h4.w * w2r[4 * u + 3];
            }
            // sum partials over p (lane bits 4,5)
            acc += __shfl_xor(acc, 16, 64);
            acc += __shfl_xor(acc, 32, 64);
            float lg = acc + cb2r;
            // softmax over k (lane bits 0..3)
            float mx = lg;
            #pragma unroll
            for (int d = 1; d < 16; d <<= 1) mx = fmaxf(mx, __shfl_xor(mx, d, 64));
            float e = __expf(lg - mx);
            float sm = e;
            #pragma unroll
            for (int d = 1; d < 16; d <<= 1) sm += __shfl_xor(sm, d, 64);
            float cko = e / sm;
            float ck[16];
            int base = l & 48;
            #pragma unroll
            for (int q = 0; q < 16; ++q) ck[q] = __shfl(cko, base + q, 64);

            #pragma unroll
            for (int m = 0; m < 7; ++m) {
                float acc2 = 0.f;
                #pragma unroll
                for (int q = 0; q < 16; ++q) acc2 += ck[q] * br[q][m];
                tm_s[ta[m]] = acc2;
            }
        }
        __syncthreads();

        // ---- FG: banded cov/mean propagation + Kalman update ----
        if (tid < 64) {
            int i = tid;
            const float* ru = tm_s + i * TMS;
            const float* rl = tm_s + (64 + i) * TMS;
            float ncu = tcu_r, ncl = tcl_r, ncs = 0.f, au = 0.f, al = 0.f;
            #pragma unroll
            for (int s = 0; s < 7; ++s) {
                float ua = ru[s], ub = ru[7 + s];
                float la = rl[s], lb = rl[7 + s];
                float cu = cuP[i + s], cs = csP[i + s], cl = clP[i + s];
                ncu += ua * ua * cu + 2.f * ua * ub * cs + ub * ub * cl;
                ncl += la * la * cu + 2.f * la * lb * cs + lb * lb * cl;
                ncs += la * ua * cu + (lb * ua + la * ub) * cs + lb * ub * cl;
                float mu = meanU[i + s], ml = meanL[i + s];
                au += ua * mu + ub * ml;
                al += la * mu + lb * ml;
            }
            float denom = ncu + wcv;
            float inv = 1.f / denom;
            float qu = ncu * inv, ql = ncs * inv;
            float res = wmv - au;
            float pmu = au + qu * res;
            float pml = al + ql * res;
            float cf = 1.f - qu;
            float pcu = cf * ncu;
            float pcl = ncl - ql * ncs;
            float pcs = cf * ncs;
            mean_s[i] = pmu; mean_s[64 + i] = pml;
            meanU[3 + i] = pmu; meanL[3 + i] = pml;
            cuP[3 + i] = pcu; clP[3 + i] = pcl; csP[3 + i] = pcs;
            post_g[rg * 128 + i] = pmu;
            post_g[rg * 128 + 64 + i] = pml;
        }
        __syncthreads();
    }
}

// ---------------- decoder (unchanged from R1) ----------------
#define DROWS 16
__global__ __launch_bounds__(256, 2)
void decoder_kernel(const float* __restrict__ post,
                    const float* __restrict__ dec_W, const float* __restrict__ dec_b,
                    const float* __restrict__ varh_W, const float* __restrict__ varh_b,
                    const float* __restrict__ var_W, const float* __restrict__ var_b,
                    float* __restrict__ out) {
    __shared__ float post_s[DROWS][LSD];
    __shared__ float vh_s[DROWS][CH];
    int tid = threadIdx.x;
    long row0 = (long)blockIdx.x * DROWS;
    for (int idx = tid; idx < DROWS * LSD; idx += 256) {
        int r = idx >> 7, c = idx & 127;
        post_s[r][c] = post[(row0 + r) * LSD + c];
    }
    __syncthreads();
    {
        int c = tid & 127, rh = tid >> 7;
        int r0 = rh * 8;
        float acc[8];
        #pragma unroll
        for (int r = 0; r < 8; ++r) acc[r] = 0.f;
        for (int j = 0; j < LSD; ++j) {
            float w = varh_W[j * CH + c];
            #pragma unroll
            for (int r = 0; r < 8; ++r) acc[r] += post_s[r0 + r][j] * w;
        }
        float bb = varh_b[c];
        #pragma unroll
        for (int r = 0; r < 8; ++r) vh_s[r0 + r][c] = fmaxf(acc[r] + bb, 0.f);
    }
    {
        int c = tid & 63, g = tid >> 6;
        int r0 = g * 4;
        float acc[4];
        #pragma unroll
        for (int r = 0; r < 4; ++r) acc[r] = 0.f;
        for (int j = 0; j < LSD; ++j) {
            float w = dec_W[j * OUTD + c];
            #pragma unroll
            for (int r = 0; r < 4; ++r) acc[r] += post_s[r0 + r][j] * w;
        }
        float bb = dec_b[c];
        #pragma unroll
        for (int r = 0; r < 4; ++r) out[(row0 + r0 + r) * 128 + c] = acc[r] + bb;
    }
    __syncthreads();
    {
        int c = tid & 63, g = tid >> 6;
        int r0 = g * 4;
        float acc[4];
        #pragma unroll
        for (int r = 0; r < 4; ++r) acc[r] = 0.f;
        for (int j = 0; j < CH; ++j) {
            float w = var_W[j * OUTD + c];
            #pragma unroll
            for (int r = 0; r < 4; ++r) acc[r] += vh_s[r0 + r][j] * w;
        }
        float bb = var_b[c];
        #pragma unroll
        for (int r = 0; r < 4; ++r) out[(row0 + r0 + r) * 128 + 64 + c] = elup1f(acc[r] + bb);
    }
}

extern "C" void kernel_launch(void* const* d_in, const int* in_sizes, int n_in,
                              void* d_out, int out_size, void* d_ws, size_t ws_size,
                              hipStream_t stream) {
    const float* obs     = (const float*)d_in[0];
    const float* enc_W   = (const float*)d_in[1];
    const float* enc_b   = (const float*)d_in[2];
    const float* wmean_W = (const float*)d_in[3];
    const float* wmean_b = (const float*)d_in[4];
    const float* wcov_W  = (const float*)d_in[5];
    const float* wcov_b  = (const float*)d_in[6];
    const float* cW1     = (const float*)d_in[7];
    const float* cb1     = (const float*)d_in[8];
    const float* cW2     = (const float*)d_in[9];
    const float* cb2     = (const float*)d_in[10];
    const float* tm11    = (const float*)d_in[11];
    const float* tm12    = (const float*)d_in[12];
    const float* tm21    = (const float*)d_in[13];
    const float* tm22    = (const float*)d_in[14];
    const float* log_tc  = (const float*)d_in[15];
    const float* dec_W   = (const float*)d_in[16];
    const float* dec_b   = (const float*)d_in[17];
    const float* varh_W  = (const float*)d_in[18];
    const float* varh_b  = (const float*)d_in[19];
    const float* var_W   = (const float*)d_in[20];
    const float* var_b   = (const float*)d_in[21];

    float* out = (float*)d_out;
    float* ws = (float*)d_ws;
    float* wm_ws    = ws;                 // 12288*64
    float* wc_ws    = ws + 786432;        // 12288*64
    float* post_ws  = ws + 1572864;       // 12288*128
    float* basis_ws = ws + 3145728;       // 16*128*14

    prep_basis<<<112, 256, 0, stream>>>(tm11, tm12, tm21, tm22, basis_ws);
    encoder_kernel<<<768, 256, 0, stream>>>(obs, enc_W, enc_b, wmean_W, wmean_b,
                                            wcov_W, wcov_b, wm_ws, wc_ws);
    scan_kernel<<<128, 256, 0, stream>>>(wm_ws, wc_ws, cW1, cb1, cW2, cb2,
                                         basis_ws, log_tc, post_ws);
    decoder_kernel<<<768, 256, 0, stream>>>(post_ws, dec_W, dec_b, varh_W, varh_b,
                                            var_W, var_b, out);
}

// Round 3
// 323.631 us; speedup vs baseline: 1.0494x; 1.0494x over previous
//
#include <hip/hip_runtime.h>
#include <math.h>

#define LOD 64
#define LSD 128
#define KK 16
#define BB 128
#define TT 96
#define OBSD 128
#define ENC 512
#define CH 128
#define OUTD 64
#define TMS 17   // tm_s row stride (odd -> 2-way bank alias max, free)

__device__ __forceinline__ float elup1f(float x) {
    return x >= 0.0f ? x + 1.0f : expf(x);
}

// ---------------- prep: band-compress basis ----------------
__global__ void prep_basis(const float* __restrict__ tm11, const float* __restrict__ tm12,
                           const float* __restrict__ tm21, const float* __restrict__ tm22,
                           float* __restrict__ basis) {
    int e = blockIdx.x * blockDim.x + threadIdx.x;
    if (e >= 16 * 128 * 14) return;
    int k = e / (128 * 14);
    int rem = e % (128 * 14);
    int row = rem / 14;
    int s = rem % 14;
    int r = row & 63;
    int half = row >> 6;
    int sub = (s >= 7) ? 1 : 0;
    int ss = s - sub * 7;
    int col = r - 3 + ss;
    float v = 0.0f;
    if (col >= 0 && col < 64) {
        const float* src = half ? (sub ? tm22 : tm21) : (sub ? tm12 : tm11);
        v = src[k * 4096 + r * 64 + col];
    }
    basis[e] = v;
}

// ---------------- encoder (unchanged) ----------------
#define EROWS 16
__global__ __launch_bounds__(256, 2)
void encoder_kernel(const float* __restrict__ obs,
                    const float* __restrict__ enc_W, const float* __restrict__ enc_b,
                    const float* __restrict__ wmean_W, const float* __restrict__ wmean_b,
                    const float* __restrict__ wcov_W, const float* __restrict__ wcov_b,
                    float* __restrict__ wm_out, float* __restrict__ wc_out) {
    __shared__ float obs_s[EROWS][OBSD];
    __shared__ float h_s[EROWS][ENC];
    __shared__ float wm_s[EROWS][LOD];
    __shared__ float norm_s[EROWS];
    int tid = threadIdx.x;
    long row0 = (long)blockIdx.x * EROWS;

    for (int idx = tid; idx < EROWS * OBSD; idx += 256) {
        int r = idx >> 7, c = idx & 127;
        obs_s[r][c] = obs[(row0 + r) * OBSD + c];
    }
    __syncthreads();

    for (int p = 0; p < 2; ++p) {
        int c = tid + p * 256;
        float acc[EROWS];
        #pragma unroll
        for (int r = 0; r < EROWS; ++r) acc[r] = 0.f;
        for (int j = 0; j < OBSD; ++j) {
            float w = enc_W[j * ENC + c];
            #pragma unroll
            for (int r = 0; r < EROWS; ++r) acc[r] += obs_s[r][j] * w;
        }
        float b = enc_b[c];
        #pragma unroll
        for (int r = 0; r < EROWS; ++r) h_s[r][c] = fmaxf(acc[r] + b, 0.f);
    }
    __syncthreads();

    {
        int c = tid & 63, g = tid >> 6;
        const float* W = (g < 2) ? wmean_W : wcov_W;
        int r0 = (g & 1) * 8;
        float acc[8];
        #pragma unroll
        for (int r = 0; r < 8; ++r) acc[r] = 0.f;
        for (int j = 0; j < ENC; ++j) {
            float w = W[j * LOD + c];
            #pragma unroll
            for (int r = 0; r < 8; ++r) acc[r] += h_s[r0 + r][j] * w;
        }
        if (g < 2) {
            float b = wmean_b[c];
            #pragma unroll
            for (int r = 0; r < 8; ++r) wm_s[r0 + r][c] = acc[r] + b;
        } else {
            float b = wcov_b[c];
            #pragma unroll
            for (int r = 0; r < 8; ++r)
                wc_out[(row0 + r0 + r) * LOD + c] = elup1f(acc[r] + b);
        }
    }
    __syncthreads();
    if (tid < EROWS) {
        float ss = 0.f;
        for (int c = 0; c < 64; ++c) { float v = wm_s[tid][c]; ss += v * v; }
        norm_s[tid] = sqrtf(ss);
    }
    __syncthreads();
    for (int idx = tid; idx < EROWS * LOD; idx += 256) {
        int r = idx >> 6, c = idx & 63;
        wm_out[(row0 + r) * LOD + c] = wm_s[r][c] / norm_s[r];
    }
}

// ---------------- scan: globally-silent main loop, 3 barriers/step ----------------
// Dynamic LDS: wm_l[96*64] | wc_l[96*64] | post_l[96*128]  (98.3 KB)
// A2 (all 256): half-dot partials of mean@cW1 (bias folded into half 0).
// CDE (all):    relu-fuse partials -> redundant per-wave logits+softmax via
//               shuffles -> banded Tm from register basis -> tm_s.
// FG (tid<64):  banded cov/mean propagation + Kalman update; wm/wc from LDS,
//               post into LDS.
__global__ __launch_bounds__(256, 1)
void scan_kernel(const float* __restrict__ wm_g, const float* __restrict__ wc_g,
                 const float* __restrict__ cW1, const float* __restrict__ cb1,
                 const float* __restrict__ cW2, const float* __restrict__ cb2,
                 const float* __restrict__ basis, const float* __restrict__ log_tc,
                 float* __restrict__ post_g) {
    extern __shared__ __align__(16) float smem[];
    float* wm_l   = smem;            // 6144
    float* wc_l   = smem + 6144;     // 6144
    float* post_l = smem + 12288;    // 12288

    __shared__ __align__(16) float mean_s[LSD];
    __shared__ __align__(16) float hpart_s[2][LSD];
    __shared__ float tm_s[128 * TMS];
    __shared__ float meanU[70], meanL[70], cuP[70], clP[70], csP[70]; // +/-3 zero pad

    int tid = threadIdx.x;
    int b = blockIdx.x;
    int l = tid & 63;
    int k = l & 15;       // logit index this lane owns
    int p = l >> 4;       // 32-wide j-chunk this lane covers

    // --- bulk-load this batch's wm/wc into LDS (one-time) ---
    {
        const float4* s0 = (const float4*)(wm_g + (long)b * (TT * 64));
        const float4* s1 = (const float4*)(wc_g + (long)b * (TT * 64));
        float4* d0 = (float4*)wm_l;
        float4* d1 = (float4*)wc_l;
        for (int idx = tid; idx < TT * 64 / 4; idx += 256) {
            d0[idx] = s0[idx];
            d1[idx] = s1[idx];
        }
    }

    // --- persistent register state ---
    float br[16][7];      // banded basis, entries e = m*256+tid for all k
    #pragma unroll
    for (int q = 0; q < 16; ++q)
        #pragma unroll
        for (int m = 0; m < 7; ++m)
            br[q][m] = basis[q * 1792 + m * 256 + tid];

    int ta[7];
    #pragma unroll
    for (int m = 0; m < 7; ++m) {
        int e = m * 256 + tid;
        ta[m] = (e / 14) * TMS + (e % 14);
    }

    int c = tid & 127, half = tid >> 7;
    float w1r[64];        // half-column of cW1: rows half*64.., col c
    #pragma unroll
    for (int jj = 0; jj < 64; ++jj)
        w1r[jj] = cW1[(half * 64 + jj) * 128 + c];
    float cb1r = (half == 0) ? cb1[c] : 0.f;

    float w2r[32];        // cW2[(p*32+u)][k]
    #pragma unroll
    for (int u = 0; u < 32; ++u)
        w2r[u] = cW2[(p * 32 + u) * 16 + k];
    float cb2r = cb2[k];

    float tcu_r = 0.f, tcl_r = 0.f;
    if (tid < 64) {
        tcu_r = elup1f(log_tc[tid]);
        tcl_r = elup1f(log_tc[64 + tid]);
    }

    // --- init carry ---
    if (tid < 70) {
        meanU[tid] = 0.f; meanL[tid] = 0.f; csP[tid] = 0.f;
        float c0 = (tid >= 3 && tid < 67) ? 10.0f : 0.f;
        cuP[tid] = c0; clP[tid] = c0;
    }
    if (tid < 128) mean_s[tid] = 0.f;
    __syncthreads();

    for (int t = 0; t < TT; ++t) {
        // ---- A2: half-dot partials ----
        {
            const float4* m4p = (const float4*)(mean_s + (half << 6));
            float a0 = 0.f, a1 = 0.f, a2 = 0.f, a3 = 0.f;
            #pragma unroll
            for (int j = 0; j < 16; ++j) {
                float4 m4 = m4p[j];
                a0 += w1r[4 * j + 0] * m4.x;
                a1 += w1r[4 * j + 1] * m4.y;
                a2 += w1r[4 * j + 2] * m4.z;
                a3 += w1r[4 * j + 3] * m4.w;
            }
            hpart_s[half][c] = a0 + a1 + a2 + a3 + cb1r;
        }
        __syncthreads();

        // ---- CDE: relu-fused logits + softmax (shuffles) + banded Tm ----
        {
            float acc = 0.f;
            const float4* hp0 = (const float4*)(hpart_s[0] + p * 32);
            const float4* hp1 = (const float4*)(hpart_s[1] + p * 32);
            #pragma unroll
            for (int u = 0; u < 8; ++u) {
                float4 q0 = hp0[u];
                float4 q1 = hp1[u];
                float h0 = fmaxf(q0.x + q1.x, 0.f);
                float h1 = fmaxf(q0.y + q1.y, 0.f);
                float h2 = fmaxf(q0.z + q1.z, 0.f);
                float h3 = fmaxf(q0.w + q1.w, 0.f);
                acc += h0 * w2r[4 * u + 0] + h1 * w2r[4 * u + 1]
                     + h2 * w2r[4 * u + 2] + h3 * w2r[4 * u + 3];
            }
            // reduce partials over p (lane bits 4,5)
            acc += __shfl_xor(acc, 16, 64);
            acc += __shfl_xor(acc, 32, 64);
            float lg = acc + cb2r;
            // softmax over k (lane bits 0..3)
            float mx = lg;
            #pragma unroll
            for (int d = 1; d < 16; d <<= 1) mx = fmaxf(mx, __shfl_xor(mx, d, 64));
            float e = __expf(lg - mx);
            float sm = e;
            #pragma unroll
            for (int d = 1; d < 16; d <<= 1) sm += __shfl_xor(sm, d, 64);
            float cko = e / sm;
            float ck[16];
            int base = l & 48;
            #pragma unroll
            for (int q = 0; q < 16; ++q) ck[q] = __shfl(cko, base + q, 64);

            #pragma unroll
            for (int m = 0; m < 7; ++m) {
                float acc2 = 0.f;
                #pragma unroll
                for (int q = 0; q < 16; ++q) acc2 += ck[q] * br[q][m];
                tm_s[ta[m]] = acc2;
            }
        }
        __syncthreads();

        // ---- FG: banded cov/mean propagation + Kalman update ----
        if (tid < 64) {
            int i = tid;
            const float* ru = tm_s + i * TMS;
            const float* rl = tm_s + (64 + i) * TMS;
            float wmv = wm_l[t * 64 + i];
            float wcv = wc_l[t * 64 + i];
            float ncu = tcu_r, ncl = tcl_r, ncs = 0.f, au = 0.f, al = 0.f;
            #pragma unroll
            for (int s = 0; s < 7; ++s) {
                float ua = ru[s], ub = ru[7 + s];
                float la = rl[s], lb = rl[7 + s];
                float cu = cuP[i + s], cs = csP[i + s], cl = clP[i + s];
                ncu += ua * ua * cu + 2.f * ua * ub * cs + ub * ub * cl;
                ncl += la * la * cu + 2.f * la * lb * cs + lb * lb * cl;
                ncs += la * ua * cu + (lb * ua + la * ub) * cs + lb * ub * cl;
                float mu = meanU[i + s], ml = meanL[i + s];
                au += ua * mu + ub * ml;
                al += la * mu + lb * ml;
            }
            float denom = ncu + wcv;
            float inv = 1.f / denom;
            float qu = ncu * inv, ql = ncs * inv;
            float res = wmv - au;
            float pmu = au + qu * res;
            float pml = al + ql * res;
            float cf = 1.f - qu;
            float pcu = cf * ncu;
            float pcl = ncl - ql * ncs;
            float pcs = cf * ncs;
            mean_s[i] = pmu; mean_s[64 + i] = pml;
            meanU[3 + i] = pmu; meanL[3 + i] = pml;
            cuP[3 + i] = pcu; clP[3 + i] = pcl; csP[3 + i] = pcs;
            post_l[t * 128 + i] = pmu;
            post_l[t * 128 + 64 + i] = pml;
        }
        __syncthreads();
    }

    // --- bulk-store post ---
    {
        const float4* s0 = (const float4*)post_l;
        float4* d0 = (float4*)(post_g + (long)b * (TT * 128));
        for (int idx = tid; idx < TT * 128 / 4; idx += 256)
            d0[idx] = s0[idx];
    }
}

// ---------------- decoder (unchanged) ----------------
#define DROWS 16
__global__ __launch_bounds__(256, 2)
void decoder_kernel(const float* __restrict__ post,
                    const float* __restrict__ dec_W, const float* __restrict__ dec_b,
                    const float* __restrict__ varh_W, const float* __restrict__ varh_b,
                    const float* __restrict__ var_W, const float* __restrict__ var_b,
                    float* __restrict__ out) {
    __shared__ float post_s[DROWS][LSD];
    __shared__ float vh_s[DROWS][CH];
    int tid = threadIdx.x;
    long row0 = (long)blockIdx.x * DROWS;
    for (int idx = tid; idx < DROWS * LSD; idx += 256) {
        int r = idx >> 7, c = idx & 127;
        post_s[r][c] = post[(row0 + r) * LSD + c];
    }
    __syncthreads();
    {
        int c = tid & 127, rh = tid >> 7;
        int r0 = rh * 8;
        float acc[8];
        #pragma unroll
        for (int r = 0; r < 8; ++r) acc[r] = 0.f;
        for (int j = 0; j < LSD; ++j) {
            float w = varh_W[j * CH + c];
            #pragma unroll
            for (int r = 0; r < 8; ++r) acc[r] += post_s[r0 + r][j] * w;
        }
        float bb = varh_b[c];
        #pragma unroll
        for (int r = 0; r < 8; ++r) vh_s[r0 + r][c] = fmaxf(acc[r] + bb, 0.f);
    }
    {
        int c = tid & 63, g = tid >> 6;
        int r0 = g * 4;
        float acc[4];
        #pragma unroll
        for (int r = 0; r < 4; ++r) acc[r] = 0.f;
        for (int j = 0; j < LSD; ++j) {
            float w = dec_W[j * OUTD + c];
            #pragma unroll
            for (int r = 0; r < 4; ++r) acc[r] += post_s[r0 + r][j] * w;
        }
        float bb = dec_b[c];
        #pragma unroll
        for (int r = 0; r < 4; ++r) out[(row0 + r0 + r) * 128 + c] = acc[r] + bb;
    }
    __syncthreads();
    {
        int c = tid & 63, g = tid >> 6;
        int r0 = g * 4;
        float acc[4];
        #pragma unroll
        for (int r = 0; r < 4; ++r) acc[r] = 0.f;
        for (int j = 0; j < CH; ++j) {
            float w = var_W[j * OUTD + c];
            #pragma unroll
            for (int r = 0; r < 4; ++r) acc[r] += vh_s[r0 + r][j] * w;
        }
        float bb = var_b[c];
        #pragma unroll
        for (int r = 0; r < 4; ++r) out[(row0 + r0 + r) * 128 + 64 + c] = elup1f(acc[r] + bb);
    }
}

extern "C" void kernel_launch(void* const* d_in, const int* in_sizes, int n_in,
                              void* d_out, int out_size, void* d_ws, size_t ws_size,
                              hipStream_t stream) {
    const float* obs     = (const float*)d_in[0];
    const float* enc_W   = (const float*)d_in[1];
    const float* enc_b   = (const float*)d_in[2];
    const float* wmean_W = (const float*)d_in[3];
    const float* wmean_b = (const float*)d_in[4];
    const float* wcov_W  = (const float*)d_in[5];
    const float* wcov_b  = (const float*)d_in[6];
    const float* cW1     = (const float*)d_in[7];
    const float* cb1     = (const float*)d_in[8];
    const float* cW2     = (const float*)d_in[9];
    const float* cb2     = (const float*)d_in[10];
    const float* tm11    = (const float*)d_in[11];
    const float* tm12    = (const float*)d_in[12];
    const float* tm21    = (const float*)d_in[13];
    const float* tm22    = (const float*)d_in[14];
    const float* log_tc  = (const float*)d_in[15];
    const float* dec_W   = (const float*)d_in[16];
    const float* dec_b   = (const float*)d_in[17];
    const float* varh_W  = (const float*)d_in[18];
    const float* varh_b  = (const float*)d_in[19];
    const float* var_W   = (const float*)d_in[20];
    const float* var_b   = (const float*)d_in[21];

    float* out = (float*)d_out;
    float* ws = (float*)d_ws;
    float* wm_ws    = ws;                 // 12288*64
    float* wc_ws    = ws + 786432;        // 12288*64
    float* post_ws  = ws + 1572864;       // 12288*128
    float* basis_ws = ws + 3145728;       // 16*128*14

    size_t dyn = (size_t)(6144 + 6144 + 12288) * sizeof(float);  // 98304 B
    static bool attr_set = false;
    if (!attr_set) {
        (void)hipFuncSetAttribute((const void*)scan_kernel,
                                  hipFuncAttributeMaxDynamicSharedMemorySize,
                                  (int)dyn);
        attr_set = true;
    }

    prep_basis<<<112, 256, 0, stream>>>(tm11, tm12, tm21, tm22, basis_ws);
    encoder_kernel<<<768, 256, 0, stream>>>(obs, enc_W, enc_b, wmean_W, wmean_b,
                                            wcov_W, wcov_b, wm_ws, wc_ws);
    scan_kernel<<<128, 256, dyn, stream>>>(wm_ws, wc_ws, cW1, cb1, cW2, cb2,
                                           basis_ws, log_tc, post_ws);
    decoder_kernel<<<768, 256, 0, stream>>>(post_ws, dec_W, dec_b, varh_W, varh_b,
                                            var_W, var_b, out);
}

// Round 4
// 316.430 us; speedup vs baseline: 1.0733x; 1.0228x over previous
//
#include <hip/hip_runtime.h>
#include <math.h>

#define LOD 64
#define LSD 128
#define KK 16
#define BB 128
#define TT 96
#define OBSD 128
#define ENC 512
#define CH 128
#define OUTD 64
#define TMS 17   // tm_s row stride (odd -> max 2-way bank alias, free)

__device__ __forceinline__ float elup1f(float x) {
    return x >= 0.0f ? x + 1.0f : expf(x);
}

// ---------------- prep: band-compress basis ----------------
__global__ void prep_basis(const float* __restrict__ tm11, const float* __restrict__ tm12,
                           const float* __restrict__ tm21, const float* __restrict__ tm22,
                           float* __restrict__ basis) {
    int e = blockIdx.x * blockDim.x + threadIdx.x;
    if (e >= 16 * 128 * 14) return;
    int k = e / (128 * 14);
    int rem = e % (128 * 14);
    int row = rem / 14;
    int s = rem % 14;
    int r = row & 63;
    int half = row >> 6;
    int sub = (s >= 7) ? 1 : 0;
    int ss = s - sub * 7;
    int col = r - 3 + ss;
    float v = 0.0f;
    if (col >= 0 && col < 64) {
        const float* src = half ? (sub ? tm22 : tm21) : (sub ? tm12 : tm11);
        v = src[k * 4096 + r * 64 + col];
    }
    basis[e] = v;
}

// ---------------- encoder (unchanged) ----------------
#define EROWS 16
__global__ __launch_bounds__(256, 2)
void encoder_kernel(const float* __restrict__ obs,
                    const float* __restrict__ enc_W, const float* __restrict__ enc_b,
                    const float* __restrict__ wmean_W, const float* __restrict__ wmean_b,
                    const float* __restrict__ wcov_W, const float* __restrict__ wcov_b,
                    float* __restrict__ wm_out, float* __restrict__ wc_out) {
    __shared__ float obs_s[EROWS][OBSD];
    __shared__ float h_s[EROWS][ENC];
    __shared__ float wm_s[EROWS][LOD];
    __shared__ float norm_s[EROWS];
    int tid = threadIdx.x;
    long row0 = (long)blockIdx.x * EROWS;

    for (int idx = tid; idx < EROWS * OBSD; idx += 256) {
        int r = idx >> 7, c = idx & 127;
        obs_s[r][c] = obs[(row0 + r) * OBSD + c];
    }
    __syncthreads();

    for (int p = 0; p < 2; ++p) {
        int c = tid + p * 256;
        float acc[EROWS];
        #pragma unroll
        for (int r = 0; r < EROWS; ++r) acc[r] = 0.f;
        for (int j = 0; j < OBSD; ++j) {
            float w = enc_W[j * ENC + c];
            #pragma unroll
            for (int r = 0; r < EROWS; ++r) acc[r] += obs_s[r][j] * w;
        }
        float b = enc_b[c];
        #pragma unroll
        for (int r = 0; r < EROWS; ++r) h_s[r][c] = fmaxf(acc[r] + b, 0.f);
    }
    __syncthreads();

    {
        int c = tid & 63, g = tid >> 6;
        const float* W = (g < 2) ? wmean_W : wcov_W;
        int r0 = (g & 1) * 8;
        float acc[8];
        #pragma unroll
        for (int r = 0; r < 8; ++r) acc[r] = 0.f;
        for (int j = 0; j < ENC; ++j) {
            float w = W[j * LOD + c];
            #pragma unroll
            for (int r = 0; r < 8; ++r) acc[r] += h_s[r0 + r][j] * w;
        }
        if (g < 2) {
            float b = wmean_b[c];
            #pragma unroll
            for (int r = 0; r < 8; ++r) wm_s[r0 + r][c] = acc[r] + b;
        } else {
            float b = wcov_b[c];
            #pragma unroll
            for (int r = 0; r < 8; ++r)
                wc_out[(row0 + r0 + r) * LOD + c] = elup1f(acc[r] + b);
        }
    }
    __syncthreads();
    if (tid < EROWS) {
        float ss = 0.f;
        for (int c = 0; c < 64; ++c) { float v = wm_s[tid][c]; ss += v * v; }
        norm_s[tid] = sqrtf(ss);
    }
    __syncthreads();
    for (int idx = tid; idx < EROWS * LOD; idx += 256) {
        int r = idx >> 6, c = idx & 63;
        wm_out[(row0 + r) * LOD + c] = wm_s[r][c] / norm_s[r];
    }
}

// ---------------- scan: redundant-wave structure, 2 barriers/step ----------------
// Every wave redundantly computes the full FG/Kalman update so the posterior
// mean is wave-local. Per step:
//   A' (in-wave): hh for wave's 32 cols from wave-private meanBr (j-split pairs)
//   P  (in-wave): partial logits for wave's cols -> part_s[16][4]
//   BARRIER A
//   Q  (in-wave): sum partials + softmax + ck gather (shuffles) + banded Tm -> tm_s
//   BARRIER B
//   FG (in-wave, redundant x4): banded cov/mean propagation + Kalman; carries in
//       wave-private LDS slices; wave 0 writes post_l.
__global__ __launch_bounds__(256, 1)
void scan_kernel(const float* __restrict__ wm_g, const float* __restrict__ wc_g,
                 const float* __restrict__ cW1, const float* __restrict__ cb1,
                 const float* __restrict__ cW2, const float* __restrict__ cb2,
                 const float* __restrict__ basis, const float* __restrict__ log_tc,
                 float* __restrict__ post_g) {
    extern __shared__ __align__(16) float smem[];
    float* wm_l   = smem;            // 6144
    float* wc_l   = smem + 6144;     // 6144
    float* post_l = smem + 12288;    // 12288

    __shared__ float tm_s[128 * TMS];
    __shared__ __align__(16) float meanBr[4][LSD];
    __shared__ __align__(16) float part_s[16][4];
    __shared__ float mu_s[4][70], ml_s[4][70];
    __shared__ float cu_s[4][70], cl_s[4][70], cs_s[4][70];

    int tid = threadIdx.x;
    int b = blockIdx.x;
    int w = tid >> 6;     // wave
    int l = tid & 63;     // lane
    int k = l & 15;       // logit index this lane owns
    int g = l >> 4;       // 8-col sub-chunk within wave's 32 cols
    int c = 32 * w + (l & 31);   // hh column this lane computes (2 lanes redundant)
    int jhalf = (l >= 32) ? 64 : 0;

    // --- bulk-load this batch's wm/wc into LDS (one-time) ---
    {
        const float4* s0 = (const float4*)(wm_g + (long)b * (TT * 64));
        const float4* s1 = (const float4*)(wc_g + (long)b * (TT * 64));
        float4* d0 = (float4*)wm_l;
        float4* d1 = (float4*)wc_l;
        for (int idx = tid; idx < TT * 64 / 4; idx += 256) {
            d0[idx] = s0[idx];
            d1[idx] = s1[idx];
        }
    }

    // --- persistent register state ---
    float br[16][7];      // banded basis, entries e = m*256+tid for all k
    #pragma unroll
    for (int q = 0; q < 16; ++q)
        #pragma unroll
        for (int m = 0; m < 7; ++m)
            br[q][m] = basis[q * 1792 + m * 256 + tid];

    int ta[7];
    #pragma unroll
    for (int m = 0; m < 7; ++m) {
        int e = m * 256 + tid;
        ta[m] = (e / 14) * TMS + (e % 14);
    }

    float w1r[64];        // cW1 rows [jhalf, jhalf+64) of column c
    #pragma unroll
    for (int jj = 0; jj < 64; ++jj)
        w1r[jj] = cW1[(jhalf + jj) * 128 + c];
    float cb1r = cb1[c];

    float w2r[8];         // cW2[(32w+8g+u)][k]
    #pragma unroll
    for (int u = 0; u < 8; ++u)
        w2r[u] = cW2[(32 * w + 8 * g + u) * 16 + k];
    float cb2r = cb2[k];

    float tcu_r = elup1f(log_tc[l]);
    float tcl_r = elup1f(log_tc[64 + l]);

    // --- init wave-private carries + mean broadcast ---
    for (int idx = l; idx < 70; idx += 64) {
        float c0 = (idx >= 3 && idx < 67) ? 10.0f : 0.f;
        cu_s[w][idx] = c0; cl_s[w][idx] = c0; cs_s[w][idx] = 0.f;
        mu_s[w][idx] = 0.f; ml_s[w][idx] = 0.f;
    }
    meanBr[w][l] = 0.f;
    meanBr[w][64 + l] = 0.f;
    __syncthreads();

    #pragma clang loop unroll(disable)
    for (int t = 0; t < TT; ++t) {
        // wm/wc for FG (LDS, issued early)
        float wmv = wm_l[t * 64 + l];
        float wcv = wc_l[t * 64 + l];

        // ---- A': hh for wave's 32 cols (j-split over lane pairs) ----
        float hh;
        {
            const float4* mp = (const float4*)(&meanBr[w][jhalf]);
            float a0 = 0.f, a1 = 0.f, a2 = 0.f, a3 = 0.f;
            #pragma unroll
            for (int j = 0; j < 16; ++j) {
                float4 m4 = mp[j];
                a0 += w1r[4 * j + 0] * m4.x;
                a1 += w1r[4 * j + 1] * m4.y;
                a2 += w1r[4 * j + 2] * m4.z;
                a3 += w1r[4 * j + 3] * m4.w;
            }
            float acc = a0 + a1 + a2 + a3;
            acc += __shfl_xor(acc, 32, 64);
            hh = fmaxf(acc + cb1r, 0.f);
        }

        // ---- P: partial logits for wave's 32 cols ----
        {
            float pacc = 0.f;
            #pragma unroll
            for (int u = 0; u < 8; ++u)
                pacc += __shfl(hh, 8 * g + u, 64) * w2r[u];
            pacc += __shfl_xor(pacc, 16, 64);
            pacc += __shfl_xor(pacc, 32, 64);
            if (l < 16) part_s[l][w] = pacc;
        }
        __syncthreads();   // BARRIER A

        // ---- Q: full logits + softmax + ck gather + banded Tm ----
        {
            float4 pv = *(const float4*)part_s[k];
            float lg = pv.x + pv.y + pv.z + pv.w + cb2r;
            float mx = lg;
            #pragma unroll
            for (int d = 1; d < 16; d <<= 1) mx = fmaxf(mx, __shfl_xor(mx, d, 64));
            float e = __expf(lg - mx);
            float sm = e;
            #pragma unroll
            for (int d = 1; d < 16; d <<= 1) sm += __shfl_xor(sm, d, 64);
            float cko = e / sm;
            float ck[16];
            int base = l & 48;
            #pragma unroll
            for (int q = 0; q < 16; ++q) ck[q] = __shfl(cko, base | q, 64);

            #pragma unroll
            for (int m = 0; m < 7; ++m) {
                float acc2 = 0.f;
                #pragma unroll
                for (int q = 0; q < 16; ++q) acc2 += ck[q] * br[q][m];
                tm_s[ta[m]] = acc2;
            }
        }
        __syncthreads();   // BARRIER B

        // ---- FG: banded cov/mean propagation + Kalman (redundant per wave) ----
        {
            int i = l;
            const float* ru = tm_s + i * TMS;
            const float* rl_ = tm_s + (64 + i) * TMS;
            float ncu = tcu_r, ncl = tcl_r, ncs = 0.f, au = 0.f, al = 0.f;
            #pragma unroll
            for (int s = 0; s < 7; ++s) {
                float ua = ru[s], ub = ru[7 + s];
                float la = rl_[s], lb = rl_[7 + s];
                float cu = cu_s[w][i + s], cs = cs_s[w][i + s], cl = cl_s[w][i + s];
                ncu += ua * ua * cu + 2.f * ua * ub * cs + ub * ub * cl;
                ncl += la * la * cu + 2.f * la * lb * cs + lb * lb * cl;
                ncs += la * ua * cu + (lb * ua + la * ub) * cs + lb * ub * cl;
                float mu = mu_s[w][i + s], ml = ml_s[w][i + s];
                au += ua * mu + ub * ml;
                al += la * mu + lb * ml;
            }
            float denom = ncu + wcv;
            float inv = 1.f / denom;
            float qu = ncu * inv, ql = ncs * inv;
            float res = wmv - au;
            float pmu = au + qu * res;
            float pml = al + ql * res;
            float cf = 1.f - qu;
            float pcu = cf * ncu;
            float pcl = ncl - ql * ncs;
            float pcs = cf * ncs;
            mu_s[w][3 + i] = pmu; ml_s[w][3 + i] = pml;
            cu_s[w][3 + i] = pcu; cl_s[w][3 + i] = pcl; cs_s[w][3 + i] = pcs;
            meanBr[w][i] = pmu; meanBr[w][64 + i] = pml;
            if (w == 0) {
                post_l[t * 128 + i] = pmu;
                post_l[t * 128 + 64 + i] = pml;
            }
        }
        // no barrier: next A'/P/FG inputs are wave-private; tm_s/part_s are
        // protected by the barrier-A/barrier-B alternation.
    }

    __syncthreads();
    // --- bulk-store post ---
    {
        const float4* s0 = (const float4*)post_l;
        float4* d0 = (float4*)(post_g + (long)b * (TT * 128));
        for (int idx = tid; idx < TT * 128 / 4; idx += 256)
            d0[idx] = s0[idx];
    }
}

// ---------------- decoder (unchanged) ----------------
#define DROWS 16
__global__ __launch_bounds__(256, 2)
void decoder_kernel(const float* __restrict__ post,
                    const float* __restrict__ dec_W, const float* __restrict__ dec_b,
                    const float* __restrict__ varh_W, const float* __restrict__ varh_b,
                    const float* __restrict__ var_W, const float* __restrict__ var_b,
                    float* __restrict__ out) {
    __shared__ float post_s[DROWS][LSD];
    __shared__ float vh_s[DROWS][CH];
    int tid = threadIdx.x;
    long row0 = (long)blockIdx.x * DROWS;
    for (int idx = tid; idx < DROWS * LSD; idx += 256) {
        int r = idx >> 7, c = idx & 127;
        post_s[r][c] = post[(row0 + r) * LSD + c];
    }
    __syncthreads();
    {
        int c = tid & 127, rh = tid >> 7;
        int r0 = rh * 8;
        float acc[8];
        #pragma unroll
        for (int r = 0; r < 8; ++r) acc[r] = 0.f;
        for (int j = 0; j < LSD; ++j) {
            float w = varh_W[j * CH + c];
            #pragma unroll
            for (int r = 0; r < 8; ++r) acc[r] += post_s[r0 + r][j] * w;
        }
        float bb = varh_b[c];
        #pragma unroll
        for (int r = 0; r < 8; ++r) vh_s[r0 + r][c] = fmaxf(acc[r] + bb, 0.f);
    }
    {
        int c = tid & 63, g = tid >> 6;
        int r0 = g * 4;
        float acc[4];
        #pragma unroll
        for (int r = 0; r < 4; ++r) acc[r] = 0.f;
        for (int j = 0; j < LSD; ++j) {
            float w = dec_W[j * OUTD + c];
            #pragma unroll
            for (int r = 0; r < 4; ++r) acc[r] += post_s[r0 + r][j] * w;
        }
        float bb = dec_b[c];
        #pragma unroll
        for (int r = 0; r < 4; ++r) out[(row0 + r0 + r) * 128 + c] = acc[r] + bb;
    }
    __syncthreads();
    {
        int c = tid & 63, g = tid >> 6;
        int r0 = g * 4;
        float acc[4];
        #pragma unroll
        for (int r = 0; r < 4; ++r) acc[r] = 0.f;
        for (int j = 0; j < CH; ++j) {
            float w = var_W[j * OUTD + c];
            #pragma unroll
            for (int r = 0; r < 4; ++r) acc[r] += vh_s[r0 + r][j] * w;
        }
        float bb = var_b[c];
        #pragma unroll
        for (int r = 0; r < 4; ++r) out[(row0 + r0 + r) * 128 + 64 + c] = elup1f(acc[r] + bb);
    }
}

extern "C" void kernel_launch(void* const* d_in, const int* in_sizes, int n_in,
                              void* d_out, int out_size, void* d_ws, size_t ws_size,
                              hipStream_t stream) {
    const float* obs     = (const float*)d_in[0];
    const float* enc_W   = (const float*)d_in[1];
    const float* enc_b   = (const float*)d_in[2];
    const float* wmean_W = (const float*)d_in[3];
    const float* wmean_b = (const float*)d_in[4];
    const float* wcov_W  = (const float*)d_in[5];
    const float* wcov_b  = (const float*)d_in[6];
    const float* cW1     = (const float*)d_in[7];
    const float* cb1     = (const float*)d_in[8];
    const float* cW2     = (const float*)d_in[9];
    const float* cb2     = (const float*)d_in[10];
    const float* tm11    = (const float*)d_in[11];
    const float* tm12    = (const float*)d_in[12];
    const float* tm21    = (const float*)d_in[13];
    const float* tm22    = (const float*)d_in[14];
    const float* log_tc  = (const float*)d_in[15];
    const float* dec_W   = (const float*)d_in[16];
    const float* dec_b   = (const float*)d_in[17];
    const float* varh_W  = (const float*)d_in[18];
    const float* varh_b  = (const float*)d_in[19];
    const float* var_W   = (const float*)d_in[20];
    const float* var_b   = (const float*)d_in[21];

    float* out = (float*)d_out;
    float* ws = (float*)d_ws;
    float* wm_ws    = ws;                 // 12288*64
    float* wc_ws    = ws + 786432;        // 12288*64
    float* post_ws  = ws + 1572864;       // 12288*128
    float* basis_ws = ws + 3145728;       // 16*128*14

    size_t dyn = (size_t)(6144 + 6144 + 12288) * sizeof(float);  // 98304 B
    (void)hipFuncSetAttribute((const void*)scan_kernel,
                              hipFuncAttributeMaxDynamicSharedMemorySize,
                              (int)dyn);

    prep_basis<<<112, 256, 0, stream>>>(tm11, tm12, tm21, tm22, basis_ws);
    encoder_kernel<<<768, 256, 0, stream>>>(obs, enc_W, enc_b, wmean_W, wmean_b,
                                            wcov_W, wcov_b, wm_ws, wc_ws);
    scan_kernel<<<128, 256, dyn, stream>>>(wm_ws, wc_ws, cW1, cb1, cW2, cb2,
                                           basis_ws, log_tc, post_ws);
    decoder_kernel<<<768, 256, 0, stream>>>(post_ws, dec_W, dec_b, varh_W, varh_b,
                                            var_W, var_b, out);
}

// Round 5
// 312.490 us; speedup vs baseline: 1.0868x; 1.0126x over previous
//
#include <hip/hip_runtime.h>
#include <math.h>

#define LOD 64
#define LSD 128
#define KK 16
#define BB 128
#define TT 96
#define OBSD 128
#define ENC 512
#define CH 128
#define OUTD 64
#define TMP 132   // tm2 row pad (per-slot rows, stride-4B lanes -> conflict-free)

__device__ __forceinline__ float elup1f(float x) {
    return x >= 0.0f ? x + 1.0f : expf(x);
}

// ---------------- prep: band-compress basis (entry e = 14*row + s) ----------------
__global__ void prep_basis(const float* __restrict__ tm11, const float* __restrict__ tm12,
                           const float* __restrict__ tm21, const float* __restrict__ tm22,
                           float* __restrict__ basis) {
    int e = blockIdx.x * blockDim.x + threadIdx.x;
    if (e >= 16 * 128 * 14) return;
    int k = e / (128 * 14);
    int rem = e % (128 * 14);
    int row = rem / 14;
    int s = rem % 14;
    int r = row & 63;
    int half = row >> 6;
    int sub = (s >= 7) ? 1 : 0;
    int ss = s - sub * 7;
    int col = r - 3 + ss;
    float v = 0.0f;
    if (col >= 0 && col < 64) {
        const float* src = half ? (sub ? tm22 : tm21) : (sub ? tm12 : tm11);
        v = src[k * 4096 + r * 64 + col];
    }
    basis[e] = v;
}

// ---------------- encoder (unchanged) ----------------
#define EROWS 16
__global__ __launch_bounds__(256, 2)
void encoder_kernel(const float* __restrict__ obs,
                    const float* __restrict__ enc_W, const float* __restrict__ enc_b,
                    const float* __restrict__ wmean_W, const float* __restrict__ wmean_b,
                    const float* __restrict__ wcov_W, const float* __restrict__ wcov_b,
                    float* __restrict__ wm_out, float* __restrict__ wc_out) {
    __shared__ float obs_s[EROWS][OBSD];
    __shared__ float h_s[EROWS][ENC];
    __shared__ float wm_s[EROWS][LOD];
    __shared__ float norm_s[EROWS];
    int tid = threadIdx.x;
    long row0 = (long)blockIdx.x * EROWS;

    for (int idx = tid; idx < EROWS * OBSD; idx += 256) {
        int r = idx >> 7, c = idx & 127;
        obs_s[r][c] = obs[(row0 + r) * OBSD + c];
    }
    __syncthreads();

    for (int p = 0; p < 2; ++p) {
        int c = tid + p * 256;
        float acc[EROWS];
        #pragma unroll
        for (int r = 0; r < EROWS; ++r) acc[r] = 0.f;
        for (int j = 0; j < OBSD; ++j) {
            float w = enc_W[j * ENC + c];
            #pragma unroll
            for (int r = 0; r < EROWS; ++r) acc[r] += obs_s[r][j] * w;
        }
        float b = enc_b[c];
        #pragma unroll
        for (int r = 0; r < EROWS; ++r) h_s[r][c] = fmaxf(acc[r] + b, 0.f);
    }
    __syncthreads();

    {
        int c = tid & 63, g = tid >> 6;
        const float* W = (g < 2) ? wmean_W : wcov_W;
        int r0 = (g & 1) * 8;
        float acc[8];
        #pragma unroll
        for (int r = 0; r < 8; ++r) acc[r] = 0.f;
        for (int j = 0; j < ENC; ++j) {
            float w = W[j * LOD + c];
            #pragma unroll
            for (int r = 0; r < 8; ++r) acc[r] += h_s[r0 + r][j] * w;
        }
        if (g < 2) {
            float b = wmean_b[c];
            #pragma unroll
            for (int r = 0; r < 8; ++r) wm_s[r0 + r][c] = acc[r] + b;
        } else {
            float b = wcov_b[c];
            #pragma unroll
            for (int r = 0; r < 8; ++r)
                wc_out[(row0 + r0 + r) * LOD + c] = elup1f(acc[r] + b);
        }
    }
    __syncthreads();
    if (tid < EROWS) {
        float ss = 0.f;
        for (int c = 0; c < 64; ++c) { float v = wm_s[tid][c]; ss += v * v; }
        norm_s[tid] = sqrtf(ss);
    }
    __syncthreads();
    for (int idx = tid; idx < EROWS * LOD; idx += 256) {
        int r = idx >> 6, c = idx & 63;
        wm_out[(row0 + r) * LOD + c] = wm_s[r][c] / norm_s[r];
    }
}

// ---------------- scan: DS-diet structure ----------------
// Per step (5 barriers):
//  P1 (all):   j-split hh partials (8 b128 reads + 2 b32 writes / wave)
//  BAR A
//  P2+L (all): combine hh (4 reads, lanes<32) -> hh_s; logit partials from
//              contiguous hh quads (2 b128) + xor16/32; write part_s
//  BAR B
//  S (w0):     16 b128 broadcast reads -> 16 logits -> in-lane exp/sum ->
//              ck_s via 4 predicated b128 writes (NO softmax shuffles)
//  BAR C
//  T (all):    4 b128 ck reads; lane owns 7 contiguous band entries ->
//              tm2[s][r] (7 conflict-free b32 writes)
//  BAR D
//  FG (w0):    28 b32 tm reads; carries in REGISTERS (18 shfl neighbors);
//              mean window prefetched at loop top; Kalman; write meanQ/post
//  BAR E
__global__ __launch_bounds__(256, 1)
void scan_kernel(const float* __restrict__ wm_g, const float* __restrict__ wc_g,
                 const float* __restrict__ cW1, const float* __restrict__ cb1,
                 const float* __restrict__ cW2, const float* __restrict__ cb2,
                 const float* __restrict__ basis, const float* __restrict__ log_tc,
                 float* __restrict__ post_g) {
    extern __shared__ __align__(16) float smem[];
    float* wm_l   = smem;            // 6144
    float* wc_l   = smem + 6144;     // 6144
    float* post_l = smem + 12288;    // 12288

    __shared__ __align__(16) float meanQ_raw[136];   // [4 pad | 128 | 4 pad]
    __shared__ __align__(16) float hpart_s[4][LSD];
    __shared__ __align__(16) float hh_s[LSD];
    __shared__ __align__(16) float part_s[4][16];
    __shared__ __align__(16) float ck_s[16];
    __shared__ float tm2[16 * TMP];                  // [slot s][row r]

    float* meanQ = meanQ_raw + 4;

    int tid = threadIdx.x;
    int b = blockIdx.x;
    int w = tid >> 6;
    int l = tid & 63;
    int k = l & 15;
    int p = l >> 4;

    // --- bulk-load this batch's wm/wc into LDS ---
    {
        const float4* s0 = (const float4*)(wm_g + (long)b * (TT * 64));
        const float4* s1 = (const float4*)(wc_g + (long)b * (TT * 64));
        float4* d0 = (float4*)wm_l;
        float4* d1 = (float4*)wc_l;
        for (int idx = tid; idx < TT * 64 / 4; idx += 256) {
            d0[idx] = s0[idx];
            d1[idx] = s1[idx];
        }
    }

    // --- persistent registers ---
    float br[16][7];             // basis entries e = 7*tid + j, all k
    #pragma unroll
    for (int q = 0; q < 16; ++q)
        #pragma unroll
        for (int j = 0; j < 7; ++j)
            br[q][j] = basis[q * 1792 + 7 * tid + j];

    float w1a[32], w1b[32];      // cW1[32w+j][l], cW1[32w+j][64+l]
    #pragma unroll
    for (int j = 0; j < 32; ++j) {
        w1a[j] = cW1[(32 * w + j) * 128 + l];
        w1b[j] = cW1[(32 * w + j) * 128 + 64 + l];
    }
    float cb1r = cb1[32 * w + (l & 31)];

    float w2r[8];                // cW2[32w+8p+u][k]
    #pragma unroll
    for (int u = 0; u < 8; ++u)
        w2r[u] = cW2[(32 * w + 8 * p + u) * 16 + k];
    float cb2r = cb2[k];

    // FG state (wave 0 only): carries in registers, lane l owns row l
    float cuR = 10.f, clR = 10.f, csR = 0.f;
    float tcu_r = elup1f(log_tc[l]);
    float tcl_r = elup1f(log_tc[64 + l]);

    // --- init shared mean (+pads) ---
    if (tid < 136) meanQ_raw[tid] = 0.f;
    __syncthreads();

    #pragma clang loop unroll(disable)
    for (int t = 0; t < TT; ++t) {
        // wave-0 prefetch: obs for FG + mean windows (latency hidden by P1..T)
        float wmv = 0.f, wcv = 0.f;
        float muw[7], mlw[7];
        if (w == 0) {
            wmv = wm_l[t * 64 + l];
            wcv = wc_l[t * 64 + l];
            #pragma unroll
            for (int d = 0; d < 7; ++d) {
                muw[d] = meanQ[l + d - 3];
                mlw[d] = meanQ[64 + l + d - 3];
            }
        }

        // ---- P1: hh partials over j in [32w, 32w+32) for cols l and 64+l ----
        {
            const float4* mq = (const float4*)(meanQ + 32 * w);
            float p0 = 0.f, p1 = 0.f;
            #pragma unroll
            for (int j = 0; j < 8; ++j) {
                float4 m4 = mq[j];
                p0 += m4.x * w1a[4 * j] + m4.y * w1a[4 * j + 1]
                    + m4.z * w1a[4 * j + 2] + m4.w * w1a[4 * j + 3];
                p1 += m4.x * w1b[4 * j] + m4.y * w1b[4 * j + 1]
                    + m4.z * w1b[4 * j + 2] + m4.w * w1b[4 * j + 3];
            }
            hpart_s[w][l] = p0;
            hpart_s[w][64 + l] = p1;
        }
        __syncthreads();   // BAR A

        // ---- P2: combine hh for wave's 32 cols; L: logit partials ----
        if (l < 32) {
            int c = 32 * w + l;
            float hv = fmaxf(hpart_s[0][c] + hpart_s[1][c] + hpart_s[2][c]
                             + hpart_s[3][c] + cb1r, 0.f);
            hh_s[c] = hv;
        }
        {
            const float4* hq = (const float4*)(hh_s + 32 * w + 8 * p);
            float4 h0 = hq[0];
            float4 h1 = hq[1];
            float pl = h0.x * w2r[0] + h0.y * w2r[1] + h0.z * w2r[2] + h0.w * w2r[3]
                     + h1.x * w2r[4] + h1.y * w2r[5] + h1.z * w2r[6] + h1.w * w2r[7];
            pl += __shfl_xor(pl, 16, 64);
            pl += __shfl_xor(pl, 32, 64);
            if (l < 16) part_s[w][l] = pl + ((w == 0) ? cb2r : 0.f);
        }
        __syncthreads();   // BAR B

        // ---- S (wave 0): in-lane softmax, no shuffles, skip max-sub ----
        if (w == 0) {
            const float4* pq = (const float4*)part_s;   // 16 quads
            float4 e0, e1, e2, e3;
            {
                float4 a = pq[0], bq = pq[4], cq = pq[8], dq = pq[12];
                e0.x = __expf(a.x + bq.x + cq.x + dq.x);
                e0.y = __expf(a.y + bq.y + cq.y + dq.y);
                e0.z = __expf(a.z + bq.z + cq.z + dq.z);
                e0.w = __expf(a.w + bq.w + cq.w + dq.w);
            }
            {
                float4 a = pq[1], bq = pq[5], cq = pq[9], dq = pq[13];
                e1.x = __expf(a.x + bq.x + cq.x + dq.x);
                e1.y = __expf(a.y + bq.y + cq.y + dq.y);
                e1.z = __expf(a.z + bq.z + cq.z + dq.z);
                e1.w = __expf(a.w + bq.w + cq.w + dq.w);
            }
            {
                float4 a = pq[2], bq = pq[6], cq = pq[10], dq = pq[14];
                e2.x = __expf(a.x + bq.x + cq.x + dq.x);
                e2.y = __expf(a.y + bq.y + cq.y + dq.y);
                e2.z = __expf(a.z + bq.z + cq.z + dq.z);
                e2.w = __expf(a.w + bq.w + cq.w + dq.w);
            }
            {
                float4 a = pq[3], bq = pq[7], cq = pq[11], dq = pq[15];
                e3.x = __expf(a.x + bq.x + cq.x + dq.x);
                e3.y = __expf(a.y + bq.y + cq.y + dq.y);
                e3.z = __expf(a.z + bq.z + cq.z + dq.z);
                e3.w = __expf(a.w + bq.w + cq.w + dq.w);
            }
            float sm = (e0.x + e0.y + e0.z + e0.w) + (e1.x + e1.y + e1.z + e1.w)
                     + (e2.x + e2.y + e2.z + e2.w) + (e3.x + e3.y + e3.z + e3.w);
            float inv = 1.f / sm;
            e0.x *= inv; e0.y *= inv; e0.z *= inv; e0.w *= inv;
            e1.x *= inv; e1.y *= inv; e1.z *= inv; e1.w *= inv;
            e2.x *= inv; e2.y *= inv; e2.z *= inv; e2.w *= inv;
            e3.x *= inv; e3.y *= inv; e3.z *= inv; e3.w *= inv;
            if (l == 0)      *(float4*)(ck_s + 0)  = e0;
            else if (l == 1) *(float4*)(ck_s + 4)  = e1;
            else if (l == 2) *(float4*)(ck_s + 8)  = e2;
            else if (l == 3) *(float4*)(ck_s + 12) = e3;
        }
        __syncthreads();   // BAR C

        // ---- T: banded Tm entries (7 contiguous per lane) ----
        {
            float4 c0 = *(const float4*)(ck_s + 0);
            float4 c1 = *(const float4*)(ck_s + 4);
            float4 c2 = *(const float4*)(ck_s + 8);
            float4 c3 = *(const float4*)(ck_s + 12);
            int r = tid >> 1;
            int s0 = (tid & 1) * 7;
            #pragma unroll
            for (int j = 0; j < 7; ++j) {
                float acc = c0.x * br[0][j] + c0.y * br[1][j] + c0.z * br[2][j] + c0.w * br[3][j]
                          + c1.x * br[4][j] + c1.y * br[5][j] + c1.z * br[6][j] + c1.w * br[7][j]
                          + c2.x * br[8][j] + c2.y * br[9][j] + c2.z * br[10][j] + c2.w * br[11][j]
                          + c3.x * br[12][j] + c3.y * br[13][j] + c3.z * br[14][j] + c3.w * br[15][j];
                tm2[(s0 + j) * TMP + r] = acc;
            }
        }
        __syncthreads();   // BAR D

        // ---- FG (wave 0): banded propagation + Kalman, carries in regs ----
        if (w == 0) {
            int i = l;
            float cun[7], csn[7], cln[7];
            #pragma unroll
            for (int d = 0; d < 7; ++d) {
                int src = i + d - 3;
                cun[d] = __shfl(cuR, src, 64);
                csn[d] = __shfl(csR, src, 64);
                cln[d] = __shfl(clR, src, 64);
            }
            float ua[7], ub[7], la[7], lb[7];
            #pragma unroll
            for (int s = 0; s < 7; ++s) {
                ua[s] = tm2[s * TMP + i];
                ub[s] = tm2[(7 + s) * TMP + i];
                la[s] = tm2[s * TMP + 64 + i];
                lb[s] = tm2[(7 + s) * TMP + 64 + i];
            }
            float ncu = tcu_r, ncl = tcl_r, ncs = 0.f, au = 0.f, al = 0.f;
            #pragma unroll
            for (int s = 0; s < 7; ++s) {
                float A = ua[s], Bv = ub[s], C = la[s], D = lb[s];
                float cu = cun[s], cs = csn[s], cl = cln[s];
                ncu += A * A * cu + 2.f * A * Bv * cs + Bv * Bv * cl;
                ncl += C * C * cu + 2.f * C * D * cs + D * D * cl;
                ncs += C * A * cu + (D * A + C * Bv) * cs + D * Bv * cl;
                au += A * muw[s] + Bv * mlw[s];
                al += C * muw[s] + D * mlw[s];
            }
            float denom = ncu + wcv;
            float inv = 1.f / denom;
            float qu = ncu * inv, ql = ncs * inv;
            float res = wmv - au;
            float pmu = au + qu * res;
            float pml = al + ql * res;
            float cf = 1.f - qu;
            cuR = cf * ncu;
            clR = ncl - ql * ncs;
            csR = cf * ncs;
            meanQ[i] = pmu;
            meanQ[64 + i] = pml;
            post_l[t * 128 + i] = pmu;
            post_l[t * 128 + 64 + i] = pml;
        }
        __syncthreads();   // BAR E
    }

    // --- bulk-store post ---
    {
        const float4* s0 = (const float4*)post_l;
        float4* d0 = (float4*)(post_g + (long)b * (TT * 128));
        for (int idx = tid; idx < TT * 128 / 4; idx += 256)
            d0[idx] = s0[idx];
    }
}

// ---------------- decoder (unchanged) ----------------
#define DROWS 16
__global__ __launch_bounds__(256, 2)
void decoder_kernel(const float* __restrict__ post,
                    const float* __restrict__ dec_W, const float* __restrict__ dec_b,
                    const float* __restrict__ varh_W, const float* __restrict__ varh_b,
                    const float* __restrict__ var_W, const float* __restrict__ var_b,
                    float* __restrict__ out) {
    __shared__ float post_s[DROWS][LSD];
    __shared__ float vh_s[DROWS][CH];
    int tid = threadIdx.x;
    long row0 = (long)blockIdx.x * DROWS;
    for (int idx = tid; idx < DROWS * LSD; idx += 256) {
        int r = idx >> 7, c = idx & 127;
        post_s[r][c] = post[(row0 + r) * LSD + c];
    }
    __syncthreads();
    {
        int c = tid & 127, rh = tid >> 7;
        int r0 = rh * 8;
        float acc[8];
        #pragma unroll
        for (int r = 0; r < 8; ++r) acc[r] = 0.f;
        for (int j = 0; j < LSD; ++j) {
            float w = varh_W[j * CH + c];
            #pragma unroll
            for (int r = 0; r < 8; ++r) acc[r] += post_s[r0 + r][j] * w;
        }
        float bb = varh_b[c];
        #pragma unroll
        for (int r = 0; r < 8; ++r) vh_s[r0 + r][c] = fmaxf(acc[r] + bb, 0.f);
    }
    {
        int c = tid & 63, g = tid >> 6;
        int r0 = g * 4;
        float acc[4];
        #pragma unroll
        for (int r = 0; r < 4; ++r) acc[r] = 0.f;
        for (int j = 0; j < LSD; ++j) {
            float w = dec_W[j * OUTD + c];
            #pragma unroll
            for (int r = 0; r < 4; ++r) acc[r] += post_s[r0 + r][j] * w;
        }
        float bb = dec_b[c];
        #pragma unroll
        for (int r = 0; r < 4; ++r) out[(row0 + r0 + r) * 128 + c] = acc[r] + bb;
    }
    __syncthreads();
    {
        int c = tid & 63, g = tid >> 6;
        int r0 = g * 4;
        float acc[4];
        #pragma unroll
        for (int r = 0; r < 4; ++r) acc[r] = 0.f;
        for (int j = 0; j < CH; ++j) {
            float w = var_W[j * OUTD + c];
            #pragma unroll
            for (int r = 0; r < 4; ++r) acc[r] += vh_s[r0 + r][j] * w;
        }
        float bb = var_b[c];
        #pragma unroll
        for (int r = 0; r < 4; ++r) out[(row0 + r0 + r) * 128 + 64 + c] = elup1f(acc[r] + bb);
    }
}

extern "C" void kernel_launch(void* const* d_in, const int* in_sizes, int n_in,
                              void* d_out, int out_size, void* d_ws, size_t ws_size,
                              hipStream_t stream) {
    const float* obs     = (const float*)d_in[0];
    const float* enc_W   = (const float*)d_in[1];
    const float* enc_b   = (const float*)d_in[2];
    const float* wmean_W = (const float*)d_in[3];
    const float* wmean_b = (const float*)d_in[4];
    const float* wcov_W  = (const float*)d_in[5];
    const float* wcov_b  = (const float*)d_in[6];
    const float* cW1     = (const float*)d_in[7];
    const float* cb1     = (const float*)d_in[8];
    const float* cW2     = (const float*)d_in[9];
    const float* cb2     = (const float*)d_in[10];
    const float* tm11    = (const float*)d_in[11];
    const float* tm12    = (const float*)d_in[12];
    const float* tm21    = (const float*)d_in[13];
    const float* tm22    = (const float*)d_in[14];
    const float* log_tc  = (const float*)d_in[15];
    const float* dec_W   = (const float*)d_in[16];
    const float* dec_b   = (const float*)d_in[17];
    const float* varh_W  = (const float*)d_in[18];
    const float* varh_b  = (const float*)d_in[19];
    const float* var_W   = (const float*)d_in[20];
    const float* var_b   = (const float*)d_in[21];

    float* out = (float*)d_out;
    float* ws = (float*)d_ws;
    float* wm_ws    = ws;                 // 12288*64
    float* wc_ws    = ws + 786432;        // 12288*64
    float* post_ws  = ws + 1572864;       // 12288*128
    float* basis_ws = ws + 3145728;       // 16*128*14

    size_t dyn = (size_t)(6144 + 6144 + 12288) * sizeof(float);  // 98304 B
    (void)hipFuncSetAttribute((const void*)scan_kernel,
                              hipFuncAttributeMaxDynamicSharedMemorySize,
                              (int)dyn);

    prep_basis<<<112, 256, 0, stream>>>(tm11, tm12, tm21, tm22, basis_ws);
    encoder_kernel<<<768, 256, 0, stream>>>(obs, enc_W, enc_b, wmean_W, wmean_b,
                                            wcov_W, wcov_b, wm_ws, wc_ws);
    scan_kernel<<<128, 256, dyn, stream>>>(wm_ws, wc_ws, cW1, cb1, cW2, cb2,
                                           basis_ws, log_tc, post_ws);
    decoder_kernel<<<768, 256, 0, stream>>>(post_ws, dec_W, dec_b, varh_W, varh_b,
                                            var_W, var_b, out);
}